// Round 2
// baseline (260.853 us; speedup 1.0000x reference)
//
#include <hip/hip_runtime.h>

// WKV (RWKV v4), fully fused single kernel.
//
// Block = 512 threads = 64 chunks x 8 channel-group threads; owns one
// (batch b, 32-channel tile). Grid = B * C/32 = 512 blocks (2/CU).
//
//   Phase 1: each thread scans its CHL=16-step chunk (4 channels, float4)
//            from identity -> local chunk state (aa,bb,pp).
//   Phase 2: Hillis-Steele exclusive scan over the 64 chunk states in LDS
//            (6 rounds, 2 barriers/round). Span of the operand at round
//            distance d is exactly d*CHL steps -> decay is d*CHL*w.
//   Phase 3: thread re-reads its chunk's k,v (L3-resident: the whole
//            128MB input was just touched) and emits y with the true
//            initial state.
//
// vs the 3-kernel version: no chunk-state HBM round-trip (-36MB traffic),
// no scan kernel (16-wg latency straggler), 1 launch instead of 3.
//
// All state in log2 domain (w,u,k pre-scaled by log2 e): every exponential
// is a bare v_exp_f32.

#define T_FIX  1024
#define NCH    64
#define CHL    (T_FIX / NCH)      // 16
#define BATCH  8
#define CTILE  32                 // channels per block (128B rows)
#define CGT    (CTILE / 4)        // 8 channel-group threads
#define NTHR   (NCH * CGT)        // 512
#define L2E    1.4426950408889634f

#define F4TOA(a, f) { a[0] = (f).x; a[1] = (f).y; a[2] = (f).z; a[3] = (f).w; }

__device__ __forceinline__ void wkv_step2(float& aa, float& bb, float& pp,
                                          float w2, float k2, float vt)
{
    float ww2 = pp + w2;
    float q2  = fmaxf(ww2, k2);
    float e1  = exp2f(ww2 - q2);
    float e2  = exp2f(k2 - q2);
    aa = fmaf(e1, aa, e2 * vt);
    bb = fmaf(e1, bb, e2);
    pp = q2;
}

__global__ __launch_bounds__(NTHR, 4)
void wkv_fused(const float* __restrict__ td,
               const float* __restrict__ tf,
               const float* __restrict__ k,
               const float* __restrict__ v,
               float* __restrict__ y,
               int B, int C)
{
    __shared__ float4 a_s[NTHR];
    __shared__ float4 b_s[NTHR];
    __shared__ float4 p_s[NTHR];

    const int tid = threadIdx.x;
    const int cg  = tid & (CGT - 1);     // channel group within tile
    const int j   = tid >> 3;            // chunk index 0..63

    const int tiles = C / CTILE;
    const int b  = blockIdx.x / tiles;
    const int c  = (blockIdx.x % tiles) * CTILE + (cg << 2);

    float4 tdv = *(const float4*)(td + c);
    float4 tfv = *(const float4*)(tf + c);
    float w2[4] = { -__expf(tdv.x) * L2E, -__expf(tdv.y) * L2E,
                    -__expf(tdv.z) * L2E, -__expf(tdv.w) * L2E };
    float u2[4] = { tfv.x * L2E, tfv.y * L2E, tfv.z * L2E, tfv.w * L2E };

    const size_t base = ((size_t)b * T_FIX + (size_t)j * CHL) * C + c;
    const float* kp = k + base;
    const float* vp = v + base;
    float*       yp = y + base;

    // ---------------- phase 1: local chunk state ----------------
    float aa[4] = {0.f, 0.f, 0.f, 0.f};
    float bb[4] = {0.f, 0.f, 0.f, 0.f};
    float pp[4] = {-1e38f, -1e38f, -1e38f, -1e38f};

    for (int tb = 0; tb < CHL; tb += BATCH) {
        float4 kb[BATCH], vb[BATCH];
        #pragma unroll
        for (int i = 0; i < BATCH; ++i) {
            kb[i] = *(const float4*)(kp + (size_t)(tb + i) * C);
            vb[i] = *(const float4*)(vp + (size_t)(tb + i) * C);
        }
        #pragma unroll
        for (int i = 0; i < BATCH; ++i) {
            float ka[4], va[4];
            F4TOA(ka, kb[i]); F4TOA(va, vb[i]);
            #pragma unroll
            for (int cc = 0; cc < 4; ++cc)
                wkv_step2(aa[cc], bb[cc], pp[cc], w2[cc], ka[cc] * L2E, va[cc]);
        }
    }

    a_s[tid] = make_float4(aa[0], aa[1], aa[2], aa[3]);
    b_s[tid] = make_float4(bb[0], bb[1], bb[2], bb[3]);
    p_s[tid] = make_float4(pp[0], pp[1], pp[2], pp[3]);
    __syncthreads();

    // ---------------- phase 2: Hillis-Steele scan over chunks ----------------
    // Inclusive scan; operand pulled from distance d spans exactly d chunks
    // for every active thread (j >= d), so its decay on the predecessor is
    // d*CHL*w.  (aa,bb,pp) registers track this thread's inclusive value.
    #pragma unroll
    for (int d = 1; d < NCH; d <<= 1) {
        float pa[4], pb[4], pm[4];
        const bool act = (j >= d);
        if (act) {
            float4 xa = a_s[tid - CGT * d];
            float4 xb = b_s[tid - CGT * d];
            float4 xp = p_s[tid - CGT * d];
            F4TOA(pa, xa); F4TOA(pb, xb); F4TOA(pm, xp);
        }
        __syncthreads();
        if (act) {
            const float Ld = (float)(d * CHL);   // steps spanned by own value
            #pragma unroll
            for (int cc = 0; cc < 4; ++cc) {
                float ppd = fmaf(Ld, w2[cc], pm[cc]);   // decay predecessor
                float pn  = fmaxf(ppd, pp[cc]);
                float ea  = exp2f(ppd - pn);
                float eb  = exp2f(pp[cc] - pn);
                aa[cc] = fmaf(ea, pa[cc], eb * aa[cc]);
                bb[cc] = fmaf(ea, pb[cc], eb * bb[cc]);
                pp[cc] = pn;
            }
            a_s[tid] = make_float4(aa[0], aa[1], aa[2], aa[3]);
            b_s[tid] = make_float4(bb[0], bb[1], bb[2], bb[3]);
            p_s[tid] = make_float4(pp[0], pp[1], pp[2], pp[3]);
        }
        __syncthreads();
    }

    // exclusive prefix for this chunk = inclusive value of chunk j-1
    if (j > 0) {
        float4 xa = a_s[tid - CGT];
        float4 xb = b_s[tid - CGT];
        float4 xp = p_s[tid - CGT];
        F4TOA(aa, xa); F4TOA(bb, xb); F4TOA(pp, xp);
    } else {
        #pragma unroll
        for (int cc = 0; cc < 4; ++cc) { aa[cc] = 0.f; bb[cc] = 0.f; pp[cc] = -1e38f; }
    }

    // ---------------- phase 3: rescan chunk, emit y ----------------
    for (int tb = 0; tb < CHL; tb += BATCH) {
        float4 kb[BATCH], vb[BATCH];
        #pragma unroll
        for (int i = 0; i < BATCH; ++i) {
            kb[i] = *(const float4*)(kp + (size_t)(tb + i) * C);
            vb[i] = *(const float4*)(vp + (size_t)(tb + i) * C);
        }
        #pragma unroll
        for (int i = 0; i < BATCH; ++i) {
            float ka[4], va[4], ya[4];
            F4TOA(ka, kb[i]); F4TOA(va, vb[i]);
            #pragma unroll
            for (int cc = 0; cc < 4; ++cc) {
                float k2 = ka[cc] * L2E;
                float ww = u2[cc] + k2;
                float q  = fmaxf(pp[cc], ww);
                float e1 = exp2f(pp[cc] - q);
                float e2 = exp2f(ww - q);
                ya[cc] = __fdividef(fmaf(e1, aa[cc], e2 * va[cc]),
                                    fmaf(e1, bb[cc], e2));
                wkv_step2(aa[cc], bb[cc], pp[cc], w2[cc], k2, va[cc]);
            }
            *(float4*)(yp + (size_t)(tb + i) * C) = make_float4(ya[0], ya[1], ya[2], ya[3]);
        }
    }
}

extern "C" void kernel_launch(void* const* d_in, const int* in_sizes, int n_in,
                              void* d_out, int out_size, void* d_ws, size_t ws_size,
                              hipStream_t stream)
{
    const float* td = (const float*)d_in[3];
    const float* tf = (const float*)d_in[4];
    const float* k  = (const float*)d_in[5];
    const float* v  = (const float*)d_in[6];
    float*       y  = (float*)d_out;

    const int C   = in_sizes[3];
    const int BTC = in_sizes[5];
    const int B   = BTC / (T_FIX * C);

    const int grid = B * (C / CTILE);
    wkv_fused<<<grid, NTHR, 0, stream>>>(td, tf, k, v, y, B, C);
}

// Round 4
// 212.194 us; speedup vs baseline: 1.2293x; 1.2293x over previous
//
#include <hip/hip_runtime.h>

// WKV (RWKV v4), fully fused single kernel.
//
// Block = 512 threads = 64 chunks x 8 channel-group threads; owns one
// (batch b, 32-channel tile). Grid = B * C/32 = 512 blocks (2/CU).
//
//   Phase 1: each thread scans its CHL=16-step chunk (4 channels, float4)
//            from identity -> local chunk state (aa,bb,pp).
//   Phase 2: Hillis-Steele exclusive scan over the 64 chunk states in LDS
//            (6 rounds). Operand at distance d spans d*CHL steps -> decay
//            is d*CHL*w.
//   Phase 3: re-read chunk's k,v (L3-resident) and emit y with the true
//            initial state.
//
// Round-2 lesson: __launch_bounds__(512,4) capped VGPRs at 64 -> the
// BATCH=8 float4 staging arrays spilled to scratch (+120MB writes,
// +60MB reads). (512,2) caps at 128 VGPRs: arrays stay in registers,
// and grid is only 2 blocks/CU anyway so nothing is lost.
//
// y stores are non-temporal (via native clang vector type — HIP float4
// is a class and __builtin_nontemporal_store rejects it): write-once data
// must not evict k,v lines other blocks' phase 3 still needs from L2/L3.
//
// All state in log2 domain (w,u,k pre-scaled by log2 e): every exponential
// is a bare v_exp_f32.

#define T_FIX  1024
#define NCH    64
#define CHL    (T_FIX / NCH)      // 16
#define BATCH  8
#define CTILE  32                 // channels per block (128B rows)
#define CGT    (CTILE / 4)        // 8 channel-group threads
#define NTHR   (NCH * CGT)        // 512
#define L2E    1.4426950408889634f

typedef float vfloat4 __attribute__((ext_vector_type(4)));

#define F4TOA(a, f) { a[0] = (f).x; a[1] = (f).y; a[2] = (f).z; a[3] = (f).w; }

__device__ __forceinline__ void wkv_step2(float& aa, float& bb, float& pp,
                                          float w2, float k2, float vt)
{
    float ww2 = pp + w2;
    float q2  = fmaxf(ww2, k2);
    float e1  = exp2f(ww2 - q2);
    float e2  = exp2f(k2 - q2);
    aa = fmaf(e1, aa, e2 * vt);
    bb = fmaf(e1, bb, e2);
    pp = q2;
}

__global__ __launch_bounds__(NTHR, 2)
void wkv_fused(const float* __restrict__ td,
               const float* __restrict__ tf,
               const float* __restrict__ k,
               const float* __restrict__ v,
               float* __restrict__ y,
               int B, int C)
{
    __shared__ float4 a_s[NTHR];
    __shared__ float4 b_s[NTHR];
    __shared__ float4 p_s[NTHR];

    const int tid = threadIdx.x;
    const int cg  = tid & (CGT - 1);     // channel group within tile
    const int j   = tid >> 3;            // chunk index 0..63

    const int tiles = C / CTILE;
    const int b  = blockIdx.x / tiles;
    const int c  = (blockIdx.x % tiles) * CTILE + (cg << 2);

    float4 tdv = *(const float4*)(td + c);
    float4 tfv = *(const float4*)(tf + c);
    float w2[4] = { -__expf(tdv.x) * L2E, -__expf(tdv.y) * L2E,
                    -__expf(tdv.z) * L2E, -__expf(tdv.w) * L2E };
    float u2[4] = { tfv.x * L2E, tfv.y * L2E, tfv.z * L2E, tfv.w * L2E };

    const size_t base = ((size_t)b * T_FIX + (size_t)j * CHL) * C + c;
    const float* kp = k + base;
    const float* vp = v + base;
    float*       yp = y + base;

    // ---------------- phase 1: local chunk state ----------------
    float aa[4] = {0.f, 0.f, 0.f, 0.f};
    float bb[4] = {0.f, 0.f, 0.f, 0.f};
    float pp[4] = {-1e38f, -1e38f, -1e38f, -1e38f};

    for (int tb = 0; tb < CHL; tb += BATCH) {
        float4 kb[BATCH], vb[BATCH];
        #pragma unroll
        for (int i = 0; i < BATCH; ++i) {
            kb[i] = *(const float4*)(kp + (size_t)(tb + i) * C);
            vb[i] = *(const float4*)(vp + (size_t)(tb + i) * C);
        }
        #pragma unroll
        for (int i = 0; i < BATCH; ++i) {
            float ka[4], va[4];
            F4TOA(ka, kb[i]); F4TOA(va, vb[i]);
            #pragma unroll
            for (int cc = 0; cc < 4; ++cc)
                wkv_step2(aa[cc], bb[cc], pp[cc], w2[cc], ka[cc] * L2E, va[cc]);
        }
    }

    a_s[tid] = make_float4(aa[0], aa[1], aa[2], aa[3]);
    b_s[tid] = make_float4(bb[0], bb[1], bb[2], bb[3]);
    p_s[tid] = make_float4(pp[0], pp[1], pp[2], pp[3]);
    __syncthreads();

    // ---------------- phase 2: Hillis-Steele scan over chunks ----------------
    #pragma unroll
    for (int d = 1; d < NCH; d <<= 1) {
        float pa[4], pb[4], pm[4];
        const bool act = (j >= d);
        if (act) {
            float4 xa = a_s[tid - CGT * d];
            float4 xb = b_s[tid - CGT * d];
            float4 xp = p_s[tid - CGT * d];
            F4TOA(pa, xa); F4TOA(pb, xb); F4TOA(pm, xp);
        }
        __syncthreads();
        if (act) {
            const float Ld = (float)(d * CHL);   // steps the own value spans
            #pragma unroll
            for (int cc = 0; cc < 4; ++cc) {
                float ppd = fmaf(Ld, w2[cc], pm[cc]);   // decay predecessor
                float pn  = fmaxf(ppd, pp[cc]);
                float ea  = exp2f(ppd - pn);
                float eb  = exp2f(pp[cc] - pn);
                aa[cc] = fmaf(ea, pa[cc], eb * aa[cc]);
                bb[cc] = fmaf(ea, pb[cc], eb * bb[cc]);
                pp[cc] = pn;
            }
            a_s[tid] = make_float4(aa[0], aa[1], aa[2], aa[3]);
            b_s[tid] = make_float4(bb[0], bb[1], bb[2], bb[3]);
            p_s[tid] = make_float4(pp[0], pp[1], pp[2], pp[3]);
        }
        __syncthreads();
    }

    // exclusive prefix for this chunk = inclusive value of chunk j-1
    if (j > 0) {
        float4 xa = a_s[tid - CGT];
        float4 xb = b_s[tid - CGT];
        float4 xp = p_s[tid - CGT];
        F4TOA(aa, xa); F4TOA(bb, xb); F4TOA(pp, xp);
    } else {
        #pragma unroll
        for (int cc = 0; cc < 4; ++cc) { aa[cc] = 0.f; bb[cc] = 0.f; pp[cc] = -1e38f; }
    }

    // ---------------- phase 3: rescan chunk, emit y ----------------
    for (int tb = 0; tb < CHL; tb += BATCH) {
        float4 kb[BATCH], vb[BATCH];
        #pragma unroll
        for (int i = 0; i < BATCH; ++i) {
            kb[i] = *(const float4*)(kp + (size_t)(tb + i) * C);
            vb[i] = *(const float4*)(vp + (size_t)(tb + i) * C);
        }
        #pragma unroll
        for (int i = 0; i < BATCH; ++i) {
            float ka[4], va[4], ya[4];
            F4TOA(ka, kb[i]); F4TOA(va, vb[i]);
            #pragma unroll
            for (int cc = 0; cc < 4; ++cc) {
                float k2 = ka[cc] * L2E;
                float ww = u2[cc] + k2;
                float q  = fmaxf(pp[cc], ww);
                float e1 = exp2f(pp[cc] - q);
                float e2 = exp2f(ww - q);
                ya[cc] = __fdividef(fmaf(e1, aa[cc], e2 * va[cc]),
                                    fmaf(e1, bb[cc], e2));
                wkv_step2(aa[cc], bb[cc], pp[cc], w2[cc], k2, va[cc]);
            }
            vfloat4 yo = { ya[0], ya[1], ya[2], ya[3] };
            __builtin_nontemporal_store(yo, (vfloat4*)(yp + (size_t)(tb + i) * C));
        }
    }
}

extern "C" void kernel_launch(void* const* d_in, const int* in_sizes, int n_in,
                              void* d_out, int out_size, void* d_ws, size_t ws_size,
                              hipStream_t stream)
{
    const float* td = (const float*)d_in[3];
    const float* tf = (const float*)d_in[4];
    const float* k  = (const float*)d_in[5];
    const float* v  = (const float*)d_in[6];
    float*       y  = (float*)d_out;

    const int C   = in_sizes[3];
    const int BTC = in_sizes[5];
    const int B   = BTC / (T_FIX * C);

    const int grid = B * (C / CTILE);
    wkv_fused<<<grid, NTHR, 0, stream>>>(td, tf, k, v, y, B, C);
}